// Round 10
// baseline (429.364 us; speedup 1.0000x reference)
//
#include <hip/hip_runtime.h>
#include <math.h>

#define TOK 4096
#define DM 2048
#define DQ 682
#define DQP 704
#define DKV 1024
#define DUKV 3072
#define NH 16
#define T_SEQ 2048
#define NQKV 1792   // 704 (padded Wdq) + 1088 (Wdkv)

typedef __attribute__((ext_vector_type(8))) short short8;
typedef __attribute__((ext_vector_type(4))) float floatx4;
typedef __attribute__((ext_vector_type(2))) unsigned int uint2v;

__device__ __forceinline__ unsigned short f2bf(float f) {
  union { float f; unsigned int u; } v; v.f = f;
  unsigned int u = v.u;
  u += 0x7fffu + ((u >> 16) & 1u);
  return (unsigned short)(u >> 16);
}
__device__ __forceinline__ unsigned short f2bf_fast(float f) {
  union { float f; unsigned int u; } v; v.f = f;
  return (unsigned short)((v.u + 0x8000u) >> 16);
}

typedef __attribute__((address_space(1))) const unsigned int as1_u32;
typedef __attribute__((address_space(3))) unsigned int as3_u32;
__device__ __forceinline__ void async16(const void* g, void* l) {
  __builtin_amdgcn_global_load_lds((as1_u32*)g, (as3_u32*)l, 16, 0, 0);
}

// ---------------------------------------------------------------------------
// bf16 MFMA GEMM, double-buffered K-loop (R9-verified). fp32 out + bias.
// ---------------------------------------------------------------------------
__global__ __launch_bounds__(256) void gemm_bf16_db(
    const unsigned short* __restrict__ A, int lda,
    const unsigned short* __restrict__ B, int ldb,
    const float* __restrict__ bias, float* __restrict__ C, int ldc,
    int Nvalid, int K)
{
  __shared__ __align__(16) unsigned short sm[16384];
  const int tid = threadIdx.x;
  const int w = tid >> 6;
  const int lane = tid & 63;
  const int q = lane >> 4;
  const int r = lane & 15;
  const int bm = blockIdx.y * 128;
  const int bn = blockIdx.x * 128;

  floatx4 acc[4][4];
#pragma unroll
  for (int i = 0; i < 4; i++)
#pragma unroll
    for (int j = 0; j < 4; j++) acc[i][j] = (floatx4){0.f, 0.f, 0.f, 0.f};

  const int srow = tid >> 2;
  const int scol = (tid & 3) * 8;
  const unsigned short* Ag0 = A + (size_t)(bm + srow) * lda + scol;
  const unsigned short* Ag1 = A + (size_t)(bm + 64 + srow) * lda + scol;
  const unsigned short* Bg0 = B + (size_t)(bn + srow) * ldb + scol;
  const unsigned short* Bg1 = B + (size_t)(bn + 64 + srow) * ldb + scol;

  const int mrow0 = (w >> 1) * 64;
  const int ncol0 = (w & 1) * 64;

  async16(Ag0, &sm[w * 512]);
  async16(Ag1, &sm[2048 + w * 512]);
  async16(Bg0, &sm[8192 + w * 512]);
  async16(Bg1, &sm[8192 + 2048 + w * 512]);

  for (int k0 = 0; k0 < K; k0 += 32) {
    const int cur = (k0 >> 5) & 1;
    __syncthreads();
    if (k0 + 32 < K) {
      const int nxt = cur ^ 1;
      async16(Ag0 + k0 + 32, &sm[nxt * 4096 + w * 512]);
      async16(Ag1 + k0 + 32, &sm[nxt * 4096 + 2048 + w * 512]);
      async16(Bg0 + k0 + 32, &sm[8192 + nxt * 4096 + w * 512]);
      async16(Bg1 + k0 + 32, &sm[8192 + nxt * 4096 + 2048 + w * 512]);
    }
    const unsigned short* As = &sm[cur * 4096];
    const unsigned short* Bs = &sm[8192 + cur * 4096];
    short8 a[4], b[4];
#pragma unroll
    for (int i = 0; i < 4; i++)
      a[i] = *(const short8*)&As[(mrow0 + i * 16 + r) * 32 + q * 8];
#pragma unroll
    for (int j = 0; j < 4; j++)
      b[j] = *(const short8*)&Bs[(ncol0 + j * 16 + r) * 32 + q * 8];
#pragma unroll
    for (int i = 0; i < 4; i++)
#pragma unroll
      for (int j = 0; j < 4; j++)
        acc[i][j] = __builtin_amdgcn_mfma_f32_16x16x32_bf16(a[i], b[j], acc[i][j], 0, 0, 0);
  }

#pragma unroll
  for (int j = 0; j < 4; j++) {
    int gc = bn + ncol0 + j * 16 + r;
    if (gc >= Nvalid) continue;
    float bv = bias[gc];
#pragma unroll
    for (int i = 0; i < 4; i++) {
#pragma unroll
      for (int v = 0; v < 4; v++) {
        int gr = bm + mrow0 + i * 16 + q * 4 + v;
        C[(size_t)gr * ldc + gc] = acc[i][j][v] + bv;
      }
    }
  }
}

// ---------------------------------------------------------------------------
// c_qkv GEMM (dbuf): fp32 out; rope cols [1728,1792) ALSO written bf16 into
// Kr_blk[b][kt][c2][64][32] (k rotary is identity; rope shared across heads).
// ---------------------------------------------------------------------------
__global__ __launch_bounds__(256) void gemm_dqkv(
    const unsigned short* __restrict__ A,
    const unsigned short* __restrict__ B,
    const float* __restrict__ bias, float* __restrict__ C,
    unsigned short* __restrict__ Kr)
{
  __shared__ __align__(16) unsigned short sm[16384];
  const int tid = threadIdx.x;
  const int w = tid >> 6;
  const int lane = tid & 63;
  const int q = lane >> 4;
  const int r = lane & 15;
  const int bm = blockIdx.y * 128;
  const int bn = blockIdx.x * 128;
  const int K = 2048;

  floatx4 acc[4][4];
#pragma unroll
  for (int i = 0; i < 4; i++)
#pragma unroll
    for (int j = 0; j < 4; j++) acc[i][j] = (floatx4){0.f, 0.f, 0.f, 0.f};

  const int srow = tid >> 2;
  const int scol = (tid & 3) * 8;
  const unsigned short* Ag0 = A + (size_t)(bm + srow) * K + scol;
  const unsigned short* Ag1 = A + (size_t)(bm + 64 + srow) * K + scol;
  const unsigned short* Bg0 = B + (size_t)(bn + srow) * K + scol;
  const unsigned short* Bg1 = B + (size_t)(bn + 64 + srow) * K + scol;

  const int mrow0 = (w >> 1) * 64;
  const int ncol0 = (w & 1) * 64;

  async16(Ag0, &sm[w * 512]);
  async16(Ag1, &sm[2048 + w * 512]);
  async16(Bg0, &sm[8192 + w * 512]);
  async16(Bg1, &sm[8192 + 2048 + w * 512]);

  for (int k0 = 0; k0 < K; k0 += 32) {
    const int cur = (k0 >> 5) & 1;
    __syncthreads();
    if (k0 + 32 < K) {
      const int nxt = cur ^ 1;
      async16(Ag0 + k0 + 32, &sm[nxt * 4096 + w * 512]);
      async16(Ag1 + k0 + 32, &sm[nxt * 4096 + 2048 + w * 512]);
      async16(Bg0 + k0 + 32, &sm[8192 + nxt * 4096 + w * 512]);
      async16(Bg1 + k0 + 32, &sm[8192 + nxt * 4096 + 2048 + w * 512]);
    }
    const unsigned short* As = &sm[cur * 4096];
    const unsigned short* Bs = &sm[8192 + cur * 4096];
    short8 a[4], b[4];
#pragma unroll
    for (int i = 0; i < 4; i++)
      a[i] = *(const short8*)&As[(mrow0 + i * 16 + r) * 32 + q * 8];
#pragma unroll
    for (int j = 0; j < 4; j++)
      b[j] = *(const short8*)&Bs[(ncol0 + j * 16 + r) * 32 + q * 8];
#pragma unroll
    for (int i = 0; i < 4; i++)
#pragma unroll
      for (int j = 0; j < 4; j++)
        acc[i][j] = __builtin_amdgcn_mfma_f32_16x16x32_bf16(a[i], b[j], acc[i][j], 0, 0, 0);
  }

#pragma unroll
  for (int j = 0; j < 4; j++) {
    int gc = bn + ncol0 + j * 16 + r;
    float bv = bias[gc];
    const bool rope = (gc >= 1728);
    const int dr = gc - 1728;
#pragma unroll
    for (int i = 0; i < 4; i++) {
#pragma unroll
      for (int v = 0; v < 4; v++) {
        int gr = bm + mrow0 + i * 16 + q * 4 + v;
        float val = acc[i][j][v] + bv;
        C[(size_t)gr * NQKV + gc] = val;
        if (rope) {
          int bb = gr >> 11, tt = gr & 2047;
          Kr[((size_t)(bb * 32 + (tt >> 6))) * 4096 + (dr >> 5) * 2048 +
             (tt & 63) * 32 + (dr & 31)] = f2bf(val);
        }
      }
    }
  }
}

// ---------------------------------------------------------------------------
// Fused up-projections (dbuf):
//  bx <  16: q-up, fused rotary+scale -> Q_all bf16 (h = bx)
//  bx >= 16: kv-up -> DIRECT tile-layout writes: Kn_blk (dd<64), V_blk (dd>=64)
// ---------------------------------------------------------------------------
__global__ __launch_bounds__(256) void gemm_up_fused(
    const unsigned short* __restrict__ Aq, const unsigned short* __restrict__ Bq,
    const float* __restrict__ biasq, unsigned short* __restrict__ Qall,
    const unsigned short* __restrict__ Akv, const unsigned short* __restrict__ Bkv,
    const float* __restrict__ biaskv,
    unsigned short* __restrict__ Kn, unsigned short* __restrict__ Vb)
{
  __shared__ __align__(16) unsigned short sm[16384];
  const int tid = threadIdx.x;
  const int w = tid >> 6;
  const int lane = tid & 63;
  const int q = lane >> 4;
  const int r = lane & 15;
  const int bx = blockIdx.x;
  const bool isQ = bx < 16;
  const int bn = isQ ? bx * 128 : (bx - 16) * 128;
  const int bm = blockIdx.y * 128;
  const int K = isQ ? DQP : DKV;
  const unsigned short* A = isQ ? Aq : Akv;
  const unsigned short* B = isQ ? Bq : Bkv;

  floatx4 acc[4][4];
#pragma unroll
  for (int i = 0; i < 4; i++)
#pragma unroll
    for (int j = 0; j < 4; j++) acc[i][j] = (floatx4){0.f, 0.f, 0.f, 0.f};

  const int srow = tid >> 2;
  const int scol = (tid & 3) * 8;
  const unsigned short* Ag0 = A + (size_t)(bm + srow) * K + scol;
  const unsigned short* Ag1 = A + (size_t)(bm + 64 + srow) * K + scol;
  const unsigned short* Bg0 = B + (size_t)(bn + srow) * K + scol;
  const unsigned short* Bg1 = B + (size_t)(bn + 64 + srow) * K + scol;

  const int mrow0 = (w >> 1) * 64;
  const int ncol0 = (w & 1) * 64;

  async16(Ag0, &sm[w * 512]);
  async16(Ag1, &sm[2048 + w * 512]);
  async16(Bg0, &sm[8192 + w * 512]);
  async16(Bg1, &sm[8192 + 2048 + w * 512]);

  for (int k0 = 0; k0 < K; k0 += 32) {
    const int cur = (k0 >> 5) & 1;
    __syncthreads();
    if (k0 + 32 < K) {
      const int nxt = cur ^ 1;
      async16(Ag0 + k0 + 32, &sm[nxt * 4096 + w * 512]);
      async16(Ag1 + k0 + 32, &sm[nxt * 4096 + 2048 + w * 512]);
      async16(Bg0 + k0 + 32, &sm[8192 + nxt * 4096 + w * 512]);
      async16(Bg1 + k0 + 32, &sm[8192 + nxt * 4096 + 2048 + w * 512]);
    }
    const unsigned short* As = &sm[cur * 4096];
    const unsigned short* Bs = &sm[8192 + cur * 4096];
    short8 a[4], b[4];
#pragma unroll
    for (int i = 0; i < 4; i++)
      a[i] = *(const short8*)&As[(mrow0 + i * 16 + r) * 32 + q * 8];
#pragma unroll
    for (int j = 0; j < 4; j++)
      b[j] = *(const short8*)&Bs[(ncol0 + j * 16 + r) * 32 + q * 8];
#pragma unroll
    for (int i = 0; i < 4; i++)
#pragma unroll
      for (int j = 0; j < 4; j++)
        acc[i][j] = __builtin_amdgcn_mfma_f32_16x16x32_bf16(a[i], b[j], acc[i][j], 0, 0, 0);
  }

  if (!isQ) {
    // direct tile-layout epilogue (replaces kv_bf + repack_k/repack_v)
#pragma unroll
    for (int j = 0; j < 4; j++) {
      int gc = bn + ncol0 + j * 16 + r;
      float bv = biaskv[gc];
      int hh = gc / 192;
      int rel = gc - hh * 192;
#pragma unroll
      for (int i = 0; i < 4; i++) {
#pragma unroll
        for (int v = 0; v < 4; v++) {
          int gr = bm + mrow0 + i * 16 + q * 4 + v;
          int bb = gr >> 11, tt = gr & 2047;
          int bhh = bb * NH + hh;
          int kt = tt >> 6;
          unsigned short val = f2bf(acc[i][j][v] + bv);
          if (rel < 64) {
            Kn[((size_t)(bhh * 32 + kt)) * 4096 + (rel >> 5) * 2048 +
               (tt & 63) * 32 + (rel & 31)] = val;
          } else {
            int d = rel - 64;
            Vb[((size_t)(bhh * 32 + kt)) * 8192 + ((tt >> 5) & 1) * 4096 +
               d * 32 + (tt & 31)] = val;
          }
        }
      }
    }
    return;
  }

  // q epilogue: fused rotary (reference quirk: angle = h * 10000^(-jj/32),
  // pairs cols d,d+32 in same thread) + scale*log2e -> Q_all bf16.
  const int h = bx;
  const float QS = (float)(0.08838834764831845 * 1.4426950408889634);
  if ((w & 1) == 0) {
#pragma unroll
    for (int j = 0; j < 4; j++) {
      int d = j * 16 + r;
      float bv = biasq[h * 128 + d];
#pragma unroll
      for (int i = 0; i < 4; i++) {
#pragma unroll
        for (int v = 0; v < 4; v++) {
          int gr = bm + mrow0 + i * 16 + q * 4 + v;
          int bb = gr >> 11, t = gr & 2047;
          Qall[(((size_t)(bb * NH + h)) * T_SEQ + t) * 128 + d] =
              f2bf((acc[i][j][v] + bv) * QS);
        }
      }
    }
  } else {
    float cs[2], sn[2], bv1[2], bv2[2];
#pragma unroll
    for (int jp = 0; jp < 2; jp++) {
      int jj = jp * 16 + r;
      float ang = (float)h * exp2f(-(float)jj * (13.287712379549449f / 32.0f));
      cs[jp] = cosf(ang); sn[jp] = sinf(ang);
      bv1[jp] = biasq[h * 128 + 64 + jj];
      bv2[jp] = biasq[h * 128 + 96 + jj];
    }
#pragma unroll
    for (int i = 0; i < 4; i++) {
#pragma unroll
      for (int v = 0; v < 4; v++) {
        int gr = bm + mrow0 + i * 16 + q * 4 + v;
        int bb = gr >> 11, t = gr & 2047;
        unsigned short* Qr = Qall + (((size_t)(bb * NH + h)) * T_SEQ + t) * 128;
#pragma unroll
        for (int jp = 0; jp < 2; jp++) {
          int jj = jp * 16 + r;
          float x1 = acc[i][jp][v] + bv1[jp];
          float x2 = acc[i][jp + 2][v] + bv2[jp];
          Qr[64 + jj] = f2bf((x1 * cs[jp] + x2 * sn[jp]) * QS);
          Qr[96 + jj] = f2bf((x2 * cs[jp] - x1 * sn[jp]) * QS);
        }
      }
    }
  }
}

// ---------------------------------------------------------------------------
__global__ __launch_bounds__(256) void cvt_bf16_pad(
    const float* __restrict__ in, unsigned short* __restrict__ out,
    int irows, int icols, int ocols, long total)
{
  long idx = (long)blockIdx.x * 256 + threadIdx.x;
  if (idx >= total) return;
  int rr = (int)(idx / ocols);
  int cc = (int)(idx - (long)rr * ocols);
  out[idx] = (rr < irows && cc < icols) ? f2bf(in[(size_t)rr * icols + cc]) : 0;
}

// ---------------------------------------------------------------------------
__device__ __forceinline__ void cvt_region(
    const float* __restrict__ in, unsigned short* __restrict__ out,
    int irows, int icols, int ocols, long idx)
{
  int rr = (int)(idx / ocols);
  int cc = (int)(idx - (long)rr * ocols);
  out[idx] = (rr < irows && cc < icols) ? f2bf(in[(size_t)rr * icols + cc]) : 0;
}

__global__ __launch_bounds__(256) void prep_weights(
    const float* __restrict__ Wdq_w, const float* __restrict__ Wdkv_w,
    const float* __restrict__ Wuq_w, const float* __restrict__ Wukv_w,
    const float* __restrict__ Wo_w,
    const float* __restrict__ Wdq_b, const float* __restrict__ Wdkv_b,
    unsigned short* __restrict__ Wqkv_bf, unsigned short* __restrict__ Wuq_bf,
    unsigned short* __restrict__ Wukv_bf, unsigned short* __restrict__ Wo_bf,
    float* __restrict__ bias_qkv)
{
  const long bx = blockIdx.x;
  if (bx < 5632) {
    cvt_region(Wdq_w, Wqkv_bf, 682, 2048, 2048, bx * 256 + threadIdx.x);
  } else if (bx < 14336) {
    cvt_region(Wdkv_w, Wqkv_bf + 704L * 2048, 1088, 2048, 2048,
               (bx - 5632) * 256 + threadIdx.x);
  } else if (bx < 19968) {
    cvt_region(Wuq_w, Wuq_bf, 2048, 682, 704, (bx - 14336) * 256 + threadIdx.x);
  } else if (bx < 32256) {
    cvt_region(Wukv_w, Wukv_bf, 3072, 1024, 1024, (bx - 19968) * 256 + threadIdx.x);
  } else if (bx < 48640) {
    cvt_region(Wo_w, Wo_bf, 2048, 2048, 2048, (bx - 32256) * 256 + threadIdx.x);
  } else {
    int i = (int)(bx - 48640) * 256 + threadIdx.x;
    if (i < NQKV)
      bias_qkv[i] = (i < DQ) ? Wdq_b[i] : ((i < DQP) ? 0.f : Wdkv_b[i - DQP]);
  }
}

// ---------------------------------------------------------------------------
// Dual LayerNorm in one launch: rows [0,4096) q-LN, [4096,8192) kv-LN.
// ---------------------------------------------------------------------------
__device__ __forceinline__ float block_sum(float v, float* sbuf) {
#pragma unroll
  for (int off = 32; off > 0; off >>= 1) v += __shfl_down(v, off, 64);
  int wid = threadIdx.x >> 6;
  __syncthreads();
  if ((threadIdx.x & 63) == 0) sbuf[wid] = v;
  __syncthreads();
  return sbuf[0] + sbuf[1] + sbuf[2] + sbuf[3];
}

__global__ __launch_bounds__(256) void ln_dual(
    const float* __restrict__ cqkv,
    unsigned short* __restrict__ outq, unsigned short* __restrict__ outkv,
    const float* __restrict__ qg, const float* __restrict__ qb,
    const float* __restrict__ kg, const float* __restrict__ kb)
{
  __shared__ float sbuf[4];
  const int row = blockIdx.x;
  const bool isQ = row < 4096;
  const int r2 = isQ ? row : row - 4096;
  const float* xr = cqkv + (size_t)r2 * NQKV + (isQ ? 0 : DQP);
  const int D = isQ ? DQ : DKV;
  const int ocols = isQ ? DQP : DKV;
  const float* g = isQ ? qg : kg;
  const float* bta = isQ ? qb : kb;
  unsigned short* orow = (isQ ? outq : outkv) + (size_t)r2 * ocols;

  float s = 0.f;
  for (int i = threadIdx.x; i < D; i += 256) s += xr[i];
  float mu = block_sum(s, sbuf) / (float)D;
  float v = 0.f;
  for (int i = threadIdx.x; i < D; i += 256) { float d = xr[i] - mu; v += d * d; }
  float var = block_sum(v, sbuf) / (float)D;
  float rstd = rsqrtf(var + 1e-5f);
  for (int i = threadIdx.x; i < ocols; i += 256)
    orow[i] = (i < D) ? f2bf((xr[i] - mu) * rstd * g[i] + bta[i]) : 0;
}

// ---------------------------------------------------------------------------
// attn v4: S^T-form MFMA flash attention, 128-row Q tiles, K/V dbuf prefetch.
// Grid 512 linear. id = xx*32 + bhid: id%8 == bhid%8 -> all 16 tiles of one
// (b,h) on one XCD (L2 locality); pair (id, id+256) has same bh and
// complementary qt = xx<8 ? xx : 23-xx (per-CU work constant AND both blocks
// stream the same K/V tiles). K image staged from Kn (per-bh) + Kr (per-b).
// ---------------------------------------------------------------------------
__global__ __launch_bounds__(256, 2) void attn_mfma4(
    const unsigned short* __restrict__ Qall,
    const unsigned short* __restrict__ Kn,
    const unsigned short* __restrict__ Kr,
    const unsigned short* __restrict__ Vb,
    unsigned short* __restrict__ y)
{
  __shared__ __align__(16) unsigned short sm[37376];
  const int id = (int)blockIdx.x;
  const int bhid = id & 31;
  const int xx = id >> 5;
  const int qt = (xx < 8) ? xx : (23 - xx);
  const int h = bhid & 15, b = bhid >> 4;
  const int tid = threadIdx.x;
  const int w = tid >> 6, lane = tid & 63, q = lane >> 4, r = lane & 15;
  const int bh = bhid;

  short8 qb[2][4];
#pragma unroll
  for (int g = 0; g < 2; g++) {
    const unsigned short* Qrow =
        Qall + ((size_t)bh * T_SEQ + (size_t)qt * 128 + w * 32 + g * 16 + r) * 128 + q * 8;
#pragma unroll
    for (int c = 0; c < 4; c++) qb[g][c] = *(const short8*)(Qrow + c * 32);
  }

  floatx4 oacc[2][8];
#pragma unroll
  for (int g = 0; g < 2; g++)
#pragma unroll
    for (int jd = 0; jd < 8; jd++) oacc[g][jd] = (floatx4){0.f, 0.f, 0.f, 0.f};
  float m_i[2] = {-3.0e38f, -3.0e38f}, l_i[2] = {0.f, 0.f};

  const char* KnG = (const char*)(Kn + (size_t)bh * 32 * 4096);
  const char* KrG = (const char*)(Kr + (size_t)b * 32 * 4096);
  const char* VG  = (const char*)(Vb + (size_t)bh * 32 * 8192);
  char* smB = (char*)sm;
  unsigned short* Psw = sm + 32768 + w * 1152;
  const int ktmax = 2 * qt + 1;

  // prologue: stage kt=0 into buffer 0
#pragma unroll
  for (int i = 0; i < 2; i++) {
    async16(KnG + i * 4096 + w * 1024 + lane * 16, smB + i * 4096 + w * 1024);
    async16(KrG + i * 4096 + w * 1024 + lane * 16, smB + 8192 + i * 4096 + w * 1024);
  }
#pragma unroll
  for (int i = 0; i < 4; i++)
    async16(VG + i * 4096 + w * 1024 + lane * 16, smB + 32768 + i * 4096 + w * 1024);

  for (int kt = 0; kt <= ktmax; kt++) {
    const int cur = kt & 1;
    __syncthreads();
    if (kt < ktmax) {
      const int nxt = cur ^ 1;
      const char* kn = KnG + (size_t)(kt + 1) * 8192;
      const char* kr = KrG + (size_t)(kt + 1) * 8192;
      const char* vg = VG + (size_t)(kt + 1) * 16384;
      char* kd = smB + nxt * 16384;
      char* vd = smB + 32768 + nxt * 16384;
#pragma unroll
      for (int i = 0; i < 2; i++) {
        async16(kn + i * 4096 + w * 1024 + lane * 16, kd + i * 4096 + w * 1024);
        async16(kr + i * 4096 + w * 1024 + lane * 16, kd + 8192 + i * 4096 + w * 1024);
      }
#pragma unroll
      for (int i = 0; i < 4; i++)
        async16(vg + i * 4096 + w * 1024 + lane * 16, vd + i * 4096 + w * 1024);
    }

    const bool activeW = (kt * 64 <= qt * 128 + w * 32 + 31);
    if (activeW) {
      const unsigned short* KsC = sm + cur * 8192;
      const unsigned short* VsC = sm + 16384 + cur * 8192;

      floatx4 sacc[2][4];
#pragma unroll
      for (int g = 0; g < 2; g++)
#pragma unroll
        for (int j = 0; j < 4; j++) sacc[g][j] = (floatx4){0.f, 0.f, 0.f, 0.f};
#pragma unroll
      for (int c = 0; c < 4; c++) {
        short8 ak[4];
#pragma unroll
        for (int j = 0; j < 4; j++)
          ak[j] = *(const short8*)&KsC[c * 2048 + (j * 16 + r) * 32 + q * 8];
#pragma unroll
        for (int g = 0; g < 2; g++)
#pragma unroll
          for (int j = 0; j < 4; j++)
            sacc[g][j] = __builtin_amdgcn_mfma_f32_16x16x32_bf16(ak[j], qb[g][c], sacc[g][j], 0, 0, 0);
      }

#pragma unroll
      for (int g = 0; g < 2; g++) {
        float sv[16];
#pragma unroll
        for (int j = 0; j < 4; j++)
#pragma unroll
          for (int v = 0; v < 4; v++) sv[j * 4 + v] = sacc[g][j][v];
        const int rel = qt * 128 + w * 32 + g * 16 + r - kt * 64;
        if (rel < 63) {
#pragma unroll
          for (int j = 0; j < 4; j++)
#pragma unroll
            for (int v = 0; v < 4; v++)
              if (j * 16 + q * 4 + v > rel) sv[j * 4 + v] = -3.0e38f;
        }
        float rm = sv[0];
#pragma unroll
        for (int t16 = 1; t16 < 16; t16++) rm = fmaxf(rm, sv[t16]);
        rm = fmaxf(rm, __shfl_xor(rm, 16, 64));
        rm = fmaxf(rm, __shfl_xor(rm, 32, 64));
        float mnew = fmaxf(m_i[g], rm);
        float alpha = exp2f(m_i[g] - mnew);
        m_i[g] = mnew;
        float p[16], rsum = 0.f;
#pragma unroll
        for (int t16 = 0; t16 < 16; t16++) { p[t16] = exp2f(sv[t16] - mnew); rsum += p[t16]; }
        rsum += __shfl_xor(rsum, 16, 64);
        rsum += __shfl_xor(rsum, 32, 64);
        l_i[g] = l_i[g] * alpha + rsum;
#pragma unroll
        for (int jd = 0; jd < 8; jd++) {
          oacc[g][jd][0] *= alpha; oacc[g][jd][1] *= alpha;
          oacc[g][jd][2] *= alpha; oacc[g][jd][3] *= alpha;
        }
#pragma unroll
        for (int j = 0; j < 4; j++) {
          unsigned int lo = (unsigned int)f2bf_fast(p[j * 4 + 0]) |
                            ((unsigned int)f2bf_fast(p[j * 4 + 1]) << 16);
          unsigned int hi = (unsigned int)f2bf_fast(p[j * 4 + 2]) |
                            ((unsigned int)f2bf_fast(p[j * 4 + 3]) << 16);
          uint2v pk; pk[0] = lo; pk[1] = hi;
          *(uint2v*)&Psw[r * 72 + j * 16 + q * 4] = pk;
        }
#pragma unroll
        for (int c2 = 0; c2 < 2; c2++) {
          short8 pb = *(const short8*)&Psw[r * 72 + c2 * 32 + q * 8];
#pragma unroll
          for (int jd = 0; jd < 8; jd++) {
            short8 bv = *(const short8*)&VsC[c2 * 4096 + (jd * 16 + r) * 32 + q * 8];
            oacc[g][jd] = __builtin_amdgcn_mfma_f32_16x16x32_bf16(bv, pb, oacc[g][jd], 0, 0, 0);
          }
        }
      }
    }
  }

#pragma unroll
  for (int g = 0; g < 2; g++) {
    float inv = 1.0f / l_i[g];
    unsigned short* yr =
        y + ((size_t)(b * T_SEQ) + (size_t)qt * 128 + w * 32 + g * 16 + r) * DM + h * 128;
#pragma unroll
    for (int jd = 0; jd < 8; jd++) {
      unsigned short o0 = f2bf(oacc[g][jd][0] * inv);
      unsigned short o1 = f2bf(oacc[g][jd][1] * inv);
      unsigned short o2 = f2bf(oacc[g][jd][2] * inv);
      unsigned short o3 = f2bf(oacc[g][jd][3] * inv);
      unsigned int lo = (unsigned int)o0 | ((unsigned int)o1 << 16);
      unsigned int hi = (unsigned int)o2 | ((unsigned int)o3 << 16);
      unsigned int* dst = (unsigned int*)(yr + jd * 16 + q * 4);
      dst[0] = lo; dst[1] = hi;
    }
  }
}

// ---------------------------------------------------------------------------
extern "C" void kernel_launch(void* const* d_in, const int* in_sizes, int n_in,
                              void* d_out, int out_size, void* d_ws, size_t ws_size,
                              hipStream_t stream) {
  const float* x      = (const float*)d_in[0];
  const float* Wdq_w  = (const float*)d_in[1];
  const float* Wdq_b  = (const float*)d_in[2];
  const float* qn_g   = (const float*)d_in[3];
  const float* qn_b   = (const float*)d_in[4];
  const float* Wuq_w  = (const float*)d_in[5];
  const float* Wuq_b  = (const float*)d_in[6];
  const float* Wdkv_w = (const float*)d_in[7];
  const float* Wdkv_b = (const float*)d_in[8];
  const float* kvn_g  = (const float*)d_in[9];
  const float* kvn_b  = (const float*)d_in[10];
  const float* Wukv_w = (const float*)d_in[11];
  const float* Wukv_b = (const float*)d_in[12];
  const float* Wo_w   = (const float*)d_in[13];
  const float* Wo_b   = (const float*)d_in[14];
  float* out = (float*)d_out;

  float* ws = (float*)d_ws;
  unsigned short* x_bf    = (unsigned short*)(ws);              // dies after c_qkv gemm
  unsigned short* y_bf    = (unsigned short*)(ws);              // alias: attn output
  unsigned short* Wqkv_bf = (unsigned short*)(ws + 4194304);    // 1792x2048
  unsigned short* Wuq_bf  = (unsigned short*)(ws + 6029312);    // 2048x704
  unsigned short* Wukv_bf = (unsigned short*)(ws + 6750208);    // 3072x1024
  float* bias_qkv = ws + 8323072;                               // 1792
  float* c_qkv    = ws + 8324864;                               // 4096x1792 fp32
  unsigned short* c_q_bf = (unsigned short*)(ws + 15664896);    // 4096x704
  unsigned short* kvn_bf = (unsigned short*)(ws + 17106688);    // 4096x1024
  unsigned short* Q_all  = (unsigned short*)(ws + 19203840);    // 2x16x2048x128
  unsigned short* Kn_blk = (unsigned short*)(ws + 23398144);    // 32bh x 32kt x 4096
  unsigned short* Kr_blk = (unsigned short*)(ws + 25495296);    // 2b x 32kt x 4096
  unsigned short* V_blk  = (unsigned short*)(ws + 25626368);    // 32bh x 32kt x 8192
  unsigned short* Wo_bf  = (unsigned short*)(ws + 29820672);    // 2048x2048

  dim3 blk(256);

  cvt_bf16_pad<<<(4096L*2048 + 255) / 256, blk, 0, stream>>>(x, x_bf, 4096, 2048, 2048, 4096L*2048);
  prep_weights<<<48647, blk, 0, stream>>>(Wdq_w, Wdkv_w, Wuq_w, Wukv_w, Wo_w,
                                          Wdq_b, Wdkv_b,
                                          Wqkv_bf, Wuq_bf, Wukv_bf, Wo_bf, bias_qkv);

  // c_qkv = x @ [Wdq; Wdkv]^T + bias; rope cols -> Kr_blk bf16
  gemm_dqkv<<<dim3(14, 32), blk, 0, stream>>>(x_bf, Wqkv_bf, bias_qkv, c_qkv, Kr_blk);
  // dual LayerNorm (q rows 0..4095, kv rows 4096..8191)
  ln_dual<<<8192, blk, 0, stream>>>(c_qkv, c_q_bf, kvn_bf, qn_g, qn_b, kvn_g, kvn_b);
  // fused up-projections: qrope -> Q_all ; kv -> Kn_blk / V_blk directly
  gemm_up_fused<<<dim3(40, 32), blk, 0, stream>>>(c_q_bf, Wuq_bf, Wuq_b, Q_all,
                                                  kvn_bf, Wukv_bf, Wukv_b,
                                                  Kn_blk, V_blk);
  // attention (XCD-swizzled linear grid)
  attn_mfma4<<<512, blk, 0, stream>>>(Q_all, Kn_blk, Kr_blk, V_blk, y_bf);
  // out = y @ Wo^T + b
  gemm_bf16_db<<<dim3(16, 32), blk, 0, stream>>>(y_bf, 2048, Wo_bf, 2048, Wo_b, out, DM, DM, 2048);
}

// Round 11
// 419.179 us; speedup vs baseline: 1.0243x; 1.0243x over previous
//
#include <hip/hip_runtime.h>
#include <math.h>

#define TOK 4096
#define DM 2048
#define DQ 682
#define DQP 704
#define DKV 1024
#define DUKV 3072
#define NH 16
#define T_SEQ 2048
#define NQKV 1792   // 704 (padded Wdq) + 1088 (Wdkv)

typedef __attribute__((ext_vector_type(8))) short short8;
typedef __attribute__((ext_vector_type(4))) float floatx4;
typedef __attribute__((ext_vector_type(2))) unsigned int uint2v;

__device__ __forceinline__ unsigned short f2bf(float f) {
  union { float f; unsigned int u; } v; v.f = f;
  unsigned int u = v.u;
  u += 0x7fffu + ((u >> 16) & 1u);
  return (unsigned short)(u >> 16);
}
__device__ __forceinline__ unsigned short f2bf_fast(float f) {
  union { float f; unsigned int u; } v; v.f = f;
  return (unsigned short)((v.u + 0x8000u) >> 16);
}

typedef __attribute__((address_space(1))) const unsigned int as1_u32;
typedef __attribute__((address_space(3))) unsigned int as3_u32;
__device__ __forceinline__ void async16(const void* g, void* l) {
  __builtin_amdgcn_global_load_lds((as1_u32*)g, (as3_u32*)l, 16, 0, 0);
}

// ---------------------------------------------------------------------------
// Split-K c_qkv GEMM (dbuf, BK=32): z=0/1 computes K-half into P0/P1 (fp32,
// no bias — bias added in the reduce). lda/ldb=2048, ldc=1792, all cols valid.
// 896 blocks -> 3.5 blocks/CU co-resident to cover HBM prefetch latency.
// ---------------------------------------------------------------------------
__global__ __launch_bounds__(256) void gemm_dqkv_sk(
    const unsigned short* __restrict__ A,
    const unsigned short* __restrict__ B,
    float* __restrict__ P0, float* __restrict__ P1)
{
  __shared__ __align__(16) unsigned short sm[16384];
  const int kz = blockIdx.z;
  const unsigned short* Ab = A + kz * 1024;
  const unsigned short* Bb = B + kz * 1024;
  float* C = kz ? P1 : P0;
  const int K = 1024;

  const int tid = threadIdx.x;
  const int w = tid >> 6, lane = tid & 63, q = lane >> 4, r = lane & 15;
  const int bm = blockIdx.y * 128, bn = blockIdx.x * 128;

  floatx4 acc[4][4];
#pragma unroll
  for (int i = 0; i < 4; i++)
#pragma unroll
    for (int j = 0; j < 4; j++) acc[i][j] = (floatx4){0.f, 0.f, 0.f, 0.f};

  const int srow = tid >> 2, scol = (tid & 3) * 8;
  const unsigned short* Ag0 = Ab + (size_t)(bm + srow) * 2048 + scol;
  const unsigned short* Ag1 = Ab + (size_t)(bm + 64 + srow) * 2048 + scol;
  const unsigned short* Bg0 = Bb + (size_t)(bn + srow) * 2048 + scol;
  const unsigned short* Bg1 = Bb + (size_t)(bn + 64 + srow) * 2048 + scol;
  const int mrow0 = (w >> 1) * 64, ncol0 = (w & 1) * 64;

  async16(Ag0, &sm[w * 512]);
  async16(Ag1, &sm[2048 + w * 512]);
  async16(Bg0, &sm[8192 + w * 512]);
  async16(Bg1, &sm[8192 + 2048 + w * 512]);

  for (int k0 = 0; k0 < K; k0 += 32) {
    const int cur = (k0 >> 5) & 1;
    __syncthreads();
    if (k0 + 32 < K) {
      const int nxt = cur ^ 1;
      async16(Ag0 + k0 + 32, &sm[nxt * 4096 + w * 512]);
      async16(Ag1 + k0 + 32, &sm[nxt * 4096 + 2048 + w * 512]);
      async16(Bg0 + k0 + 32, &sm[8192 + nxt * 4096 + w * 512]);
      async16(Bg1 + k0 + 32, &sm[8192 + nxt * 4096 + 2048 + w * 512]);
    }
    const unsigned short* As = &sm[cur * 4096];
    const unsigned short* Bs = &sm[8192 + cur * 4096];
    short8 a[4], b[4];
#pragma unroll
    for (int i = 0; i < 4; i++)
      a[i] = *(const short8*)&As[(mrow0 + i * 16 + r) * 32 + q * 8];
#pragma unroll
    for (int j = 0; j < 4; j++)
      b[j] = *(const short8*)&Bs[(ncol0 + j * 16 + r) * 32 + q * 8];
#pragma unroll
    for (int i = 0; i < 4; i++)
#pragma unroll
      for (int j = 0; j < 4; j++)
        acc[i][j] = __builtin_amdgcn_mfma_f32_16x16x32_bf16(a[i], b[j], acc[i][j], 0, 0, 0);
  }

#pragma unroll
  for (int j = 0; j < 4; j++) {
    int gc = bn + ncol0 + j * 16 + r;
#pragma unroll
    for (int i = 0; i < 4; i++) {
#pragma unroll
      for (int v = 0; v < 4; v++) {
        int gr = bm + mrow0 + i * 16 + q * 4 + v;
        C[(size_t)gr * NQKV + gc] = acc[i][j][v];
      }
    }
  }
}

// ---------------------------------------------------------------------------
// Wo GEMM, BK=64 dbuf: LDS image chunked [c2][128][32] (identical bank-safe
// addressing to BK=32, doubled). 64 KB LDS, 2 blocks/CU (grid 512 = exact).
// Halves barrier count; doubles compute per barrier window.
// ---------------------------------------------------------------------------
__global__ __launch_bounds__(256) void gemm_wo64(
    const unsigned short* __restrict__ A,
    const unsigned short* __restrict__ B,
    const float* __restrict__ bias, float* __restrict__ C)
{
  __shared__ __align__(16) unsigned short sm[32768]; // A:2x8192 @0, B:@16384
  const int tid = threadIdx.x;
  const int w = tid >> 6, lane = tid & 63, q = lane >> 4, r = lane & 15;
  const int bm = blockIdx.y * 128, bn = blockIdx.x * 128;

  floatx4 acc[4][4];
#pragma unroll
  for (int i = 0; i < 4; i++)
#pragma unroll
    for (int j = 0; j < 4; j++) acc[i][j] = (floatx4){0.f, 0.f, 0.f, 0.f};

  const int srow = tid >> 2, scol = (tid & 3) * 8;
  const unsigned short* Ag0 = A + (size_t)(bm + srow) * 2048 + scol;
  const unsigned short* Ag1 = A + (size_t)(bm + 64 + srow) * 2048 + scol;
  const unsigned short* Bg0 = B + (size_t)(bn + srow) * 2048 + scol;
  const unsigned short* Bg1 = B + (size_t)(bn + 64 + srow) * 2048 + scol;
  const int mrow0 = (w >> 1) * 64, ncol0 = (w & 1) * 64;

#pragma unroll
  for (int c2 = 0; c2 < 2; c2++) {
    async16(Ag0 + c2 * 32, &sm[c2 * 4096 + w * 512]);
    async16(Ag1 + c2 * 32, &sm[c2 * 4096 + 2048 + w * 512]);
    async16(Bg0 + c2 * 32, &sm[16384 + c2 * 4096 + w * 512]);
    async16(Bg1 + c2 * 32, &sm[16384 + c2 * 4096 + 2048 + w * 512]);
  }

  for (int k0 = 0; k0 < 2048; k0 += 64) {
    const int cur = (k0 >> 6) & 1;
    __syncthreads();
    if (k0 + 64 < 2048) {
      const int nxt = cur ^ 1;
#pragma unroll
      for (int c2 = 0; c2 < 2; c2++) {
        async16(Ag0 + k0 + 64 + c2 * 32, &sm[nxt * 8192 + c2 * 4096 + w * 512]);
        async16(Ag1 + k0 + 64 + c2 * 32, &sm[nxt * 8192 + c2 * 4096 + 2048 + w * 512]);
        async16(Bg0 + k0 + 64 + c2 * 32, &sm[16384 + nxt * 8192 + c2 * 4096 + w * 512]);
        async16(Bg1 + k0 + 64 + c2 * 32, &sm[16384 + nxt * 8192 + c2 * 4096 + 2048 + w * 512]);
      }
    }
#pragma unroll
    for (int c2 = 0; c2 < 2; c2++) {
      const unsigned short* As = &sm[cur * 8192 + c2 * 4096];
      const unsigned short* Bs = &sm[16384 + cur * 8192 + c2 * 4096];
      short8 a[4], b[4];
#pragma unroll
      for (int i = 0; i < 4; i++)
        a[i] = *(const short8*)&As[(mrow0 + i * 16 + r) * 32 + q * 8];
#pragma unroll
      for (int j = 0; j < 4; j++)
        b[j] = *(const short8*)&Bs[(ncol0 + j * 16 + r) * 32 + q * 8];
#pragma unroll
      for (int i = 0; i < 4; i++)
#pragma unroll
        for (int j = 0; j < 4; j++)
          acc[i][j] = __builtin_amdgcn_mfma_f32_16x16x32_bf16(a[i], b[j], acc[i][j], 0, 0, 0);
    }
  }

#pragma unroll
  for (int j = 0; j < 4; j++) {
    int gc = bn + ncol0 + j * 16 + r;
    float bv = bias[gc];
#pragma unroll
    for (int i = 0; i < 4; i++) {
#pragma unroll
      for (int v = 0; v < 4; v++) {
        int gr = bm + mrow0 + i * 16 + q * 4 + v;
        C[(size_t)gr * 2048 + gc] = acc[i][j][v] + bv;
      }
    }
  }
}

// ---------------------------------------------------------------------------
// Fused up-projections (dbuf, R10-verified):
//  bx <  16: q-up, fused rotary+scale -> Q_all bf16 (h = bx)
//  bx >= 16: kv-up -> direct tile writes: Kn_blk (dd<64), V_blk (dd>=64)
// ---------------------------------------------------------------------------
__global__ __launch_bounds__(256) void gemm_up_fused(
    const unsigned short* __restrict__ Aq, const unsigned short* __restrict__ Bq,
    const float* __restrict__ biasq, unsigned short* __restrict__ Qall,
    const unsigned short* __restrict__ Akv, const unsigned short* __restrict__ Bkv,
    const float* __restrict__ biaskv,
    unsigned short* __restrict__ Kn, unsigned short* __restrict__ Vb)
{
  __shared__ __align__(16) unsigned short sm[16384];
  const int tid = threadIdx.x;
  const int w = tid >> 6, lane = tid & 63, q = lane >> 4, r = lane & 15;
  const int bx = blockIdx.x;
  const bool isQ = bx < 16;
  const int bn = isQ ? bx * 128 : (bx - 16) * 128;
  const int bm = blockIdx.y * 128;
  const int K = isQ ? DQP : DKV;
  const unsigned short* A = isQ ? Aq : Akv;
  const unsigned short* B = isQ ? Bq : Bkv;

  floatx4 acc[4][4];
#pragma unroll
  for (int i = 0; i < 4; i++)
#pragma unroll
    for (int j = 0; j < 4; j++) acc[i][j] = (floatx4){0.f, 0.f, 0.f, 0.f};

  const int srow = tid >> 2, scol = (tid & 3) * 8;
  const unsigned short* Ag0 = A + (size_t)(bm + srow) * K + scol;
  const unsigned short* Ag1 = A + (size_t)(bm + 64 + srow) * K + scol;
  const unsigned short* Bg0 = B + (size_t)(bn + srow) * K + scol;
  const unsigned short* Bg1 = B + (size_t)(bn + 64 + srow) * K + scol;
  const int mrow0 = (w >> 1) * 64, ncol0 = (w & 1) * 64;

  async16(Ag0, &sm[w * 512]);
  async16(Ag1, &sm[2048 + w * 512]);
  async16(Bg0, &sm[8192 + w * 512]);
  async16(Bg1, &sm[8192 + 2048 + w * 512]);

  for (int k0 = 0; k0 < K; k0 += 32) {
    const int cur = (k0 >> 5) & 1;
    __syncthreads();
    if (k0 + 32 < K) {
      const int nxt = cur ^ 1;
      async16(Ag0 + k0 + 32, &sm[nxt * 4096 + w * 512]);
      async16(Ag1 + k0 + 32, &sm[nxt * 4096 + 2048 + w * 512]);
      async16(Bg0 + k0 + 32, &sm[8192 + nxt * 4096 + w * 512]);
      async16(Bg1 + k0 + 32, &sm[8192 + nxt * 4096 + 2048 + w * 512]);
    }
    const unsigned short* As = &sm[cur * 4096];
    const unsigned short* Bs = &sm[8192 + cur * 4096];
    short8 a[4], b[4];
#pragma unroll
    for (int i = 0; i < 4; i++)
      a[i] = *(const short8*)&As[(mrow0 + i * 16 + r) * 32 + q * 8];
#pragma unroll
    for (int j = 0; j < 4; j++)
      b[j] = *(const short8*)&Bs[(ncol0 + j * 16 + r) * 32 + q * 8];
#pragma unroll
    for (int i = 0; i < 4; i++)
#pragma unroll
      for (int j = 0; j < 4; j++)
        acc[i][j] = __builtin_amdgcn_mfma_f32_16x16x32_bf16(a[i], b[j], acc[i][j], 0, 0, 0);
  }

  if (!isQ) {
#pragma unroll
    for (int j = 0; j < 4; j++) {
      int gc = bn + ncol0 + j * 16 + r;
      float bv = biaskv[gc];
      int hh = gc / 192;
      int rel = gc - hh * 192;
#pragma unroll
      for (int i = 0; i < 4; i++) {
#pragma unroll
        for (int v = 0; v < 4; v++) {
          int gr = bm + mrow0 + i * 16 + q * 4 + v;
          int bb = gr >> 11, tt = gr & 2047;
          int bhh = bb * NH + hh;
          int kt = tt >> 6;
          unsigned short val = f2bf(acc[i][j][v] + bv);
          if (rel < 64) {
            Kn[((size_t)(bhh * 32 + kt)) * 4096 + (rel >> 5) * 2048 +
               (tt & 63) * 32 + (rel & 31)] = val;
          } else {
            int d = rel - 64;
            Vb[((size_t)(bhh * 32 + kt)) * 8192 + ((tt >> 5) & 1) * 4096 +
               d * 32 + (tt & 31)] = val;
          }
        }
      }
    }
    return;
  }

  const int h = bx;
  const float QS = (float)(0.08838834764831845 * 1.4426950408889634);
  if ((w & 1) == 0) {
#pragma unroll
    for (int j = 0; j < 4; j++) {
      int d = j * 16 + r;
      float bv = biasq[h * 128 + d];
#pragma unroll
      for (int i = 0; i < 4; i++) {
#pragma unroll
        for (int v = 0; v < 4; v++) {
          int gr = bm + mrow0 + i * 16 + q * 4 + v;
          int bb = gr >> 11, t = gr & 2047;
          Qall[(((size_t)(bb * NH + h)) * T_SEQ + t) * 128 + d] =
              f2bf((acc[i][j][v] + bv) * QS);
        }
      }
    }
  } else {
    float cs[2], sn[2], bv1[2], bv2[2];
#pragma unroll
    for (int jp = 0; jp < 2; jp++) {
      int jj = jp * 16 + r;
      float ang = (float)h * exp2f(-(float)jj * (13.287712379549449f / 32.0f));
      cs[jp] = cosf(ang); sn[jp] = sinf(ang);
      bv1[jp] = biasq[h * 128 + 64 + jj];
      bv2[jp] = biasq[h * 128 + 96 + jj];
    }
#pragma unroll
    for (int i = 0; i < 4; i++) {
#pragma unroll
      for (int v = 0; v < 4; v++) {
        int gr = bm + mrow0 + i * 16 + q * 4 + v;
        int bb = gr >> 11, t = gr & 2047;
        unsigned short* Qr = Qall + (((size_t)(bb * NH + h)) * T_SEQ + t) * 128;
#pragma unroll
        for (int jp = 0; jp < 2; jp++) {
          int jj = jp * 16 + r;
          float x1 = acc[i][jp][v] + bv1[jp];
          float x2 = acc[i][jp + 2][v] + bv2[jp];
          Qr[64 + jj] = f2bf((x1 * cs[jp] + x2 * sn[jp]) * QS);
          Qr[96 + jj] = f2bf((x2 * cs[jp] - x1 * sn[jp]) * QS);
        }
      }
    }
  }
}

// ---------------------------------------------------------------------------
// One prep launch: x cvt + 5 weight cvts + bias concat (block-range dispatch).
// ---------------------------------------------------------------------------
__device__ __forceinline__ void cvt_region(
    const float* __restrict__ in, unsigned short* __restrict__ out,
    int irows, int icols, int ocols, long idx)
{
  int rr = (int)(idx / ocols);
  int cc = (int)(idx - (long)rr * ocols);
  out[idx] = (rr < irows && cc < icols) ? f2bf(in[(size_t)rr * icols + cc]) : 0;
}

__global__ __launch_bounds__(256) void prep_all(
    const float* __restrict__ x,
    const float* __restrict__ Wdq_w, const float* __restrict__ Wdkv_w,
    const float* __restrict__ Wuq_w, const float* __restrict__ Wukv_w,
    const float* __restrict__ Wo_w,
    const float* __restrict__ Wdq_b, const float* __restrict__ Wdkv_b,
    unsigned short* __restrict__ x_bf,
    unsigned short* __restrict__ Wqkv_bf, unsigned short* __restrict__ Wuq_bf,
    unsigned short* __restrict__ Wukv_bf, unsigned short* __restrict__ Wo_bf,
    float* __restrict__ bias_qkv)
{
  const long bx = blockIdx.x;
  if (bx < 32768) {
    long idx = bx * 256 + threadIdx.x;
    x_bf[idx] = f2bf(x[idx]);
  } else if (bx < 38400) {
    cvt_region(Wdq_w, Wqkv_bf, 682, 2048, 2048, (bx - 32768) * 256 + threadIdx.x);
  } else if (bx < 47104) {
    cvt_region(Wdkv_w, Wqkv_bf + 704L * 2048, 1088, 2048, 2048,
               (bx - 38400) * 256 + threadIdx.x);
  } else if (bx < 52736) {
    cvt_region(Wuq_w, Wuq_bf, 2048, 682, 704, (bx - 47104) * 256 + threadIdx.x);
  } else if (bx < 65024) {
    cvt_region(Wukv_w, Wukv_bf, 3072, 1024, 1024, (bx - 52736) * 256 + threadIdx.x);
  } else if (bx < 81408) {
    cvt_region(Wo_w, Wo_bf, 2048, 2048, 2048, (bx - 65024) * 256 + threadIdx.x);
  } else {
    int i = (int)(bx - 81408) * 256 + threadIdx.x;
    if (i < NQKV)
      bias_qkv[i] = (i < DQ) ? Wdq_b[i] : ((i < DQP) ? 0.f : Wdkv_b[i - DQP]);
  }
}

// ---------------------------------------------------------------------------
// ln_dual_r: reduce split-K partials (p0+p1+bias) + LayerNorm (single-pass
// sum/sumsq, 2 read-passes) for q rows [0,4096) and kv rows [4096,8192);
// blocks >= 8192 sum+convert rope cols [1728,1792) into Kr_blk tile layout.
// ---------------------------------------------------------------------------
__global__ __launch_bounds__(256) void ln_dual_r(
    const float* __restrict__ p0, const float* __restrict__ p1,
    const float* __restrict__ bqkv,
    unsigned short* __restrict__ outq, unsigned short* __restrict__ outkv,
    unsigned short* __restrict__ Kr,
    const float* __restrict__ qg, const float* __restrict__ qb2,
    const float* __restrict__ kg, const float* __restrict__ kb2)
{
  __shared__ float sbuf[8];
  const int blk = blockIdx.x;
  if (blk >= 8192) {
    const int base = (blk - 8192) * 512;
#pragma unroll
    for (int s = 0; s < 2; s++) {
      int idx = base + s * 256 + threadIdx.x;
      int row = idx >> 6, dr = idx & 63;
      size_t off = (size_t)row * NQKV + 1728 + dr;
      float v = p0[off] + p1[off] + bqkv[1728 + dr];
      Kr[((size_t)((row >> 11) * 32 + ((row & 2047) >> 6))) * 4096 +
         (dr >> 5) * 2048 + (row & 63) * 32 + (dr & 31)] = f2bf(v);
    }
    return;
  }
  const bool isQ = blk < 4096;
  const int r2 = isQ ? blk : blk - 4096;
  const int off = isQ ? 0 : DQP;
  const float* x0 = p0 + (size_t)r2 * NQKV + off;
  const float* x1 = p1 + (size_t)r2 * NQKV + off;
  const float* bb = bqkv + off;
  const int D = isQ ? DQ : DKV;
  const int ocols = isQ ? DQP : DKV;
  const float* g = isQ ? qg : kg;
  const float* bta = isQ ? qb2 : kb2;
  unsigned short* orow = (isQ ? outq : outkv) + (size_t)r2 * ocols;

  float s = 0.f, s2 = 0.f;
  for (int i = threadIdx.x; i < D; i += 256) {
    float v = x0[i] + x1[i] + bb[i];
    s += v; s2 += v * v;
  }
#pragma unroll
  for (int o = 32; o > 0; o >>= 1) {
    s += __shfl_down(s, o, 64);
    s2 += __shfl_down(s2, o, 64);
  }
  int wid = threadIdx.x >> 6;
  __syncthreads();
  if ((threadIdx.x & 63) == 0) { sbuf[wid] = s; sbuf[4 + wid] = s2; }
  __syncthreads();
  float su = sbuf[0] + sbuf[1] + sbuf[2] + sbuf[3];
  float sq = sbuf[4] + sbuf[5] + sbuf[6] + sbuf[7];
  float mu = su / (float)D;
  float var = sq / (float)D - mu * mu;
  float rstd = rsqrtf(var + 1e-5f);
  for (int i = threadIdx.x; i < ocols; i += 256) {
    float v = (i < D) ? ((x0[i] + x1[i] + bb[i]) - mu) * rstd * g[i] + bta[i] : 0.f;
    orow[i] = (i < D) ? f2bf(v) : 0;
  }
}

// ---------------------------------------------------------------------------
// attn v4 (R10-verified): S^T-form MFMA flash attention, XCD-swizzled grid.
// ---------------------------------------------------------------------------
__global__ __launch_bounds__(256, 2) void attn_mfma4(
    const unsigned short* __restrict__ Qall,
    const unsigned short* __restrict__ Kn,
    const unsigned short* __restrict__ Kr,
    const unsigned short* __restrict__ Vb,
    unsigned short* __restrict__ y)
{
  __shared__ __align__(16) unsigned short sm[37376];
  const int id = (int)blockIdx.x;
  const int bhid = id & 31;
  const int xx = id >> 5;
  const int qt = (xx < 8) ? xx : (23 - xx);
  const int h = bhid & 15, b = bhid >> 4;
  const int tid = threadIdx.x;
  const int w = tid >> 6, lane = tid & 63, q = lane >> 4, r = lane & 15;
  const int bh = bhid;

  short8 qb[2][4];
#pragma unroll
  for (int g = 0; g < 2; g++) {
    const unsigned short* Qrow =
        Qall + ((size_t)bh * T_SEQ + (size_t)qt * 128 + w * 32 + g * 16 + r) * 128 + q * 8;
#pragma unroll
    for (int c = 0; c < 4; c++) qb[g][c] = *(const short8*)(Qrow + c * 32);
  }

  floatx4 oacc[2][8];
#pragma unroll
  for (int g = 0; g < 2; g++)
#pragma unroll
    for (int jd = 0; jd < 8; jd++) oacc[g][jd] = (floatx4){0.f, 0.f, 0.f, 0.f};
  float m_i[2] = {-3.0e38f, -3.0e38f}, l_i[2] = {0.f, 0.f};

  const char* KnG = (const char*)(Kn + (size_t)bh * 32 * 4096);
  const char* KrG = (const char*)(Kr + (size_t)b * 32 * 4096);
  const char* VG  = (const char*)(Vb + (size_t)bh * 32 * 8192);
  char* smB = (char*)sm;
  unsigned short* Psw = sm + 32768 + w * 1152;
  const int ktmax = 2 * qt + 1;

#pragma unroll
  for (int i = 0; i < 2; i++) {
    async16(KnG + i * 4096 + w * 1024 + lane * 16, smB + i * 4096 + w * 1024);
    async16(KrG + i * 4096 + w * 1024 + lane * 16, smB + 8192 + i * 4096 + w * 1024);
  }
#pragma unroll
  for (int i = 0; i < 4; i++)
    async16(VG + i * 4096 + w * 1024 + lane * 16, smB + 32768 + i * 4096 + w * 1024);

  for (int kt = 0; kt <= ktmax; kt++) {
    const int cur = kt & 1;
    __syncthreads();
    if (kt < ktmax) {
      const int nxt = cur ^ 1;
      const char* kn = KnG + (size_t)(kt + 1) * 8192;
      const char* kr = KrG + (size_t)(kt + 1) * 8192;
      const char* vg = VG + (size_t)(kt + 1) * 16384;
      char* kd = smB + nxt * 16384;
      char* vd = smB + 32768 + nxt * 16384;
#pragma unroll
      for (int i = 0; i < 2; i++) {
        async16(kn + i * 4096 + w * 1024 + lane * 16, kd + i * 4096 + w * 1024);
        async16(kr + i * 4096 + w * 1024 + lane * 16, kd + 8192 + i * 4096 + w * 1024);
      }
#pragma unroll
      for (int i = 0; i < 4; i++)
        async16(vg + i * 4096 + w * 1024 + lane * 16, vd + i * 4096 + w * 1024);
    }

    const bool activeW = (kt * 64 <= qt * 128 + w * 32 + 31);
    if (activeW) {
      const unsigned short* KsC = sm + cur * 8192;
      const unsigned short* VsC = sm + 16384 + cur * 8192;

      floatx4 sacc[2][4];
#pragma unroll
      for (int g = 0; g < 2; g++)
#pragma unroll
        for (int j = 0; j < 4; j++) sacc[g][j] = (floatx4){0.f, 0.f, 0.f, 0.f};
#pragma unroll
      for (int c = 0; c < 4; c++) {
        short8 ak[4];
#pragma unroll
        for (int j = 0; j < 4; j++)
          ak[j] = *(const short8*)&KsC[c * 2048 + (j * 16 + r) * 32 + q * 8];
#pragma unroll
        for (int g = 0; g < 2; g++)
#pragma unroll
          for (int j = 0; j < 4; j++)
            sacc[g][j] = __builtin_amdgcn_mfma_f32_16x16x32_bf16(ak[j], qb[g][c], sacc[g][j], 0, 0, 0);
      }

#pragma unroll
      for (int g = 0; g < 2; g++) {
        float sv[16];
#pragma unroll
        for (int j = 0; j < 4; j++)
#pragma unroll
          for (int v = 0; v < 4; v++) sv[j * 4 + v] = sacc[g][j][v];
        const int rel = qt * 128 + w * 32 + g * 16 + r - kt * 64;
        if (rel < 63) {
#pragma unroll
          for (int j = 0; j < 4; j++)
#pragma unroll
            for (int v = 0; v < 4; v++)
              if (j * 16 + q * 4 + v > rel) sv[j * 4 + v] = -3.0e38f;
        }
        float rm = sv[0];
#pragma unroll
        for (int t16 = 1; t16 < 16; t16++) rm = fmaxf(rm, sv[t16]);
        rm = fmaxf(rm, __shfl_xor(rm, 16, 64));
        rm = fmaxf(rm, __shfl_xor(rm, 32, 64));
        float mnew = fmaxf(m_i[g], rm);
        float alpha = exp2f(m_i[g] - mnew);
        m_i[g] = mnew;
        float p[16], rsum = 0.f;
#pragma unroll
        for (int t16 = 0; t16 < 16; t16++) { p[t16] = exp2f(sv[t16] - mnew); rsum += p[t16]; }
        rsum += __shfl_xor(rsum, 16, 64);
        rsum += __shfl_xor(rsum, 32, 64);
        l_i[g] = l_i[g] * alpha + rsum;
#pragma unroll
        for (int jd = 0; jd < 8; jd++) {
          oacc[g][jd][0] *= alpha; oacc[g][jd][1] *= alpha;
          oacc[g][jd][2] *= alpha; oacc[g][jd][3] *= alpha;
        }
#pragma unroll
        for (int j = 0; j < 4; j++) {
          unsigned int lo = (unsigned int)f2bf_fast(p[j * 4 + 0]) |
                            ((unsigned int)f2bf_fast(p[j * 4 + 1]) << 16);
          unsigned int hi = (unsigned int)f2bf_fast(p[j * 4 + 2]) |
                            ((unsigned int)f2bf_fast(p[j * 4 + 3]) << 16);
          uint2v pk; pk[0] = lo; pk[1] = hi;
          *(uint2v*)&Psw[r * 72 + j * 16 + q * 4] = pk;
        }
#pragma unroll
        for (int c2 = 0; c2 < 2; c2++) {
          short8 pb = *(const short8*)&Psw[r * 72 + c2 * 32 + q * 8];
#pragma unroll
          for (int jd = 0; jd < 8; jd++) {
            short8 bv = *(const short8*)&VsC[c2 * 4096 + (jd * 16 + r) * 32 + q * 8];
            oacc[g][jd] = __builtin_amdgcn_mfma_f32_16x16x32_bf16(bv, pb, oacc[g][jd], 0, 0, 0);
          }
        }
      }
    }
  }

#pragma unroll
  for (int g = 0; g < 2; g++) {
    float inv = 1.0f / l_i[g];
    unsigned short* yr =
        y + ((size_t)(b * T_SEQ) + (size_t)qt * 128 + w * 32 + g * 16 + r) * DM + h * 128;
#pragma unroll
    for (int jd = 0; jd < 8; jd++) {
      unsigned short o0 = f2bf(oacc[g][jd][0] * inv);
      unsigned short o1 = f2bf(oacc[g][jd][1] * inv);
      unsigned short o2 = f2bf(oacc[g][jd][2] * inv);
      unsigned short o3 = f2bf(oacc[g][jd][3] * inv);
      unsigned int lo = (unsigned int)o0 | ((unsigned int)o1 << 16);
      unsigned int hi = (unsigned int)o2 | ((unsigned int)o3 << 16);
      unsigned int* dst = (unsigned int*)(yr + jd * 16 + q * 4);
      dst[0] = lo; dst[1] = hi;
    }
  }
}

// ---------------------------------------------------------------------------
extern "C" void kernel_launch(void* const* d_in, const int* in_sizes, int n_in,
                              void* d_out, int out_size, void* d_ws, size_t ws_size,
                              hipStream_t stream) {
  const float* x      = (const float*)d_in[0];
  const float* Wdq_w  = (const float*)d_in[1];
  const float* Wdq_b  = (const float*)d_in[2];
  const float* qn_g   = (const float*)d_in[3];
  const float* qn_b   = (const float*)d_in[4];
  const float* Wuq_w  = (const float*)d_in[5];
  const float* Wuq_b  = (const float*)d_in[6];
  const float* Wdkv_w = (const float*)d_in[7];
  const float* Wdkv_b = (const float*)d_in[8];
  const float* kvn_g  = (const float*)d_in[9];
  const float* kvn_b  = (const float*)d_in[10];
  const float* Wukv_w = (const float*)d_in[11];
  const float* Wukv_b = (const float*)d_in[12];
  const float* Wo_w   = (const float*)d_in[13];
  const float* Wo_b   = (const float*)d_in[14];
  float* out = (float*)d_out;

  float* ws = (float*)d_ws;
  unsigned short* x_bf    = (unsigned short*)(ws);              // dies after dqkv gemm
  unsigned short* y_bf    = (unsigned short*)(ws);              // alias: attn output
  unsigned short* Wqkv_bf = (unsigned short*)(ws + 4194304);    // 1792x2048
  unsigned short* Wuq_bf  = (unsigned short*)(ws + 6029312);    // 2048x704
  unsigned short* Wukv_bf = (unsigned short*)(ws + 6750208);    // 3072x1024
  float* bias_qkv = ws + 8323072;                               // 1792
  float* p0       = ws + 8324864;                               // 4096x1792 fp32
  float* p1       = ws + 15664896;                              // 4096x1792 fp32
  unsigned short* c_q_bf = (unsigned short*)(ws + 23004928);    // 4096x704
  unsigned short* kvn_bf = (unsigned short*)(ws + 24446720);    // 4096x1024
  unsigned short* Q_all  = (unsigned short*)(ws + 26543872);    // 2x16x2048x128
  unsigned short* Kn_blk = (unsigned short*)(ws + 30738176);    // 32bh x 32kt x 4096
  unsigned short* Kr_blk = (unsigned short*)(ws + 32835328);    // 2b x 32kt x 4096
  unsigned short* V_blk  = (unsigned short*)(ws + 32966400);    // 32bh x 32kt x 8192
  unsigned short* Wo_bf  = (unsigned short*)(ws + 37160704);    // 2048x2048

  dim3 blk(256);

  // one prep launch: x cvt + weights + bias concat
  prep_all<<<81415, blk, 0, stream>>>(x, Wdq_w, Wdkv_w, Wuq_w, Wukv_w, Wo_w,
                                      Wdq_b, Wdkv_b,
                                      x_bf, Wqkv_bf, Wuq_bf, Wukv_bf, Wo_bf,
                                      bias_qkv);
  // split-K c_qkv partials (896 blocks)
  gemm_dqkv_sk<<<dim3(14, 32, 2), blk, 0, stream>>>(x_bf, Wqkv_bf, p0, p1);
  // reduce + dual LN + rope->Kr_blk
  ln_dual_r<<<8704, blk, 0, stream>>>(p0, p1, bias_qkv, c_q_bf, kvn_bf, Kr_blk,
                                      qn_g, qn_b, kvn_g, kvn_b);
  // fused up-projections: qrope -> Q_all ; kv -> Kn_blk / V_blk
  gemm_up_fused<<<dim3(40, 32), blk, 0, stream>>>(c_q_bf, Wuq_bf, Wuq_b, Q_all,
                                                  kvn_bf, Wukv_bf, Wukv_b,
                                                  Kn_blk, V_blk);
  // attention
  attn_mfma4<<<512, blk, 0, stream>>>(Q_all, Kn_blk, Kr_blk, V_blk, y_bf);
  // out = y @ Wo^T + b (BK=64 dbuf)
  gemm_wo64<<<dim3(16, 32), blk, 0, stream>>>(y_bf, Wo_bf, Wo_b, out);
}